// Round 1
// baseline (256.135 us; speedup 1.0000x reference)
//
#include <hip/hip_runtime.h>

// PyramidROIAlign: B=2, N=1000, C=256, pool 7x7, levels p2..p5 (256,128,64,32), NHWC fp32.
// One 64-thread block per output cell (b,n,py,px). lane = float4 channel group.

#define NB 2
#define NN 1000
#define NC 256
#define PHW 7

__global__ __launch_bounds__(64) void roi_align_kernel(
    const float* __restrict__ boxes,
    const float* __restrict__ p2,
    const float* __restrict__ p3,
    const float* __restrict__ p4,
    const float* __restrict__ p5,
    float* __restrict__ out)
{
    const int cell = blockIdx.x;            // 0 .. NB*NN*49-1
    const int tid  = threadIdx.x;           // 0..63  (float4 channel group)

    const int pxy = cell % 49;
    const int bn  = cell / 49;
    const int py  = pxy / 7;
    const int px  = pxy % 7;
    const int b   = bn / NN;

    // Box
    const float* bx = boxes + (size_t)bn * 4;
    const float y1 = bx[0], x1 = bx[1], y2 = bx[2], x2 = bx[3];
    const float h = y2 - y1, w = x2 - x1;

    // roi_level = clip(round(log2(sqrt(max(h*w,1e-12)) / (224/1024))), 2, 5)
    // rintf = round-half-to-even, matching jnp.round.
    const float roi = log2f(sqrtf(fmaxf(h * w, 1e-12f)) * (1024.0f / 224.0f));
    int lvl = (int)rintf(roi);
    lvl = min(5, max(2, lvl));

    const float* feat;
    int H;
    switch (lvl) {
        case 2:  feat = p2; H = 256; break;
        case 3:  feat = p3; H = 128; break;
        case 4:  feat = p4; H = 64;  break;
        default: feat = p5; H = 32;  break;
    }
    const int W = H;

    // Sample coords: ys = (y1 + h*ty)*(H-1), ty = py/6
    const float ys = (y1 + h * ((float)py * (1.0f / 6.0f))) * (float)(H - 1);
    const float xs = (x1 + w * ((float)px * (1.0f / 6.0f))) * (float)(W - 1);
    const float y0f = floorf(ys), x0f = floorf(xs);
    const float wy = ys - y0f;
    const float wx = xs - x0f;
    const int y0 = min(H - 1, max(0, (int)y0f));
    const int yb = min(H - 1, max(0, (int)y0f + 1));
    const int x0 = min(W - 1, max(0, (int)x0f));
    const int xb = min(W - 1, max(0, (int)x0f + 1));

    const size_t base = (size_t)b * H * W * NC;
    const float4* r00 = (const float4*)(feat + base + ((size_t)y0 * W + x0) * NC);
    const float4* r01 = (const float4*)(feat + base + ((size_t)y0 * W + xb) * NC);
    const float4* r10 = (const float4*)(feat + base + ((size_t)yb * W + x0) * NC);
    const float4* r11 = (const float4*)(feat + base + ((size_t)yb * W + xb) * NC);

    const float4 v00 = r00[tid];
    const float4 v01 = r01[tid];
    const float4 v10 = r10[tid];
    const float4 v11 = r11[tid];

    float4 res;
    {
        float t, bo;
        t  = v00.x + wx * (v01.x - v00.x);
        bo = v10.x + wx * (v11.x - v10.x);
        res.x = t + wy * (bo - t);
        t  = v00.y + wx * (v01.y - v00.y);
        bo = v10.y + wx * (v11.y - v10.y);
        res.y = t + wy * (bo - t);
        t  = v00.z + wx * (v01.z - v00.z);
        bo = v10.z + wx * (v11.z - v10.z);
        res.z = t + wy * (bo - t);
        t  = v00.w + wx * (v01.w - v00.w);
        bo = v10.w + wx * (v11.w - v10.w);
        res.w = t + wy * (bo - t);
    }

    float4* o = (float4*)(out + (size_t)cell * NC);
    o[tid] = res;
}

extern "C" void kernel_launch(void* const* d_in, const int* in_sizes, int n_in,
                              void* d_out, int out_size, void* d_ws, size_t ws_size,
                              hipStream_t stream) {
    const float* boxes = (const float*)d_in[0];
    const float* p2    = (const float*)d_in[1];
    const float* p3    = (const float*)d_in[2];
    const float* p4    = (const float*)d_in[3];
    const float* p5    = (const float*)d_in[4];
    float* out = (float*)d_out;

    const int n_cells = NB * NN * PHW * PHW;  // 98000
    roi_align_kernel<<<n_cells, 64, 0, stream>>>(boxes, p2, p3, p4, p5, out);
}

// Round 3
// 255.771 us; speedup vs baseline: 1.0014x; 1.0014x over previous
//
#include <hip/hip_runtime.h>

// PyramidROIAlign: B=2, N=1000, C=256, pool 7x7, levels p2..p5 (256,128,64,32), NHWC fp32.
// 256-thread blocks, 4 waves; each wave processes 2 consecutive cells interleaved
// (8 corner loads in flight). lane = float4 channel group. Non-temporal output stores.

#define NB 2
#define NN 1000
#define NC 256
#define NCELLS (NB * NN * 49)   // 98000
#define CELLS_PER_BLOCK 8       // 4 waves x 2 cells

typedef float vfloat4 __attribute__((ext_vector_type(4)));  // clang-native, ok for nontemporal builtins

__device__ __forceinline__ void cell_setup(
    int cell,
    const float* __restrict__ boxes,
    const float* __restrict__ p2, const float* __restrict__ p3,
    const float* __restrict__ p4, const float* __restrict__ p5,
    const vfloat4*& a00, const vfloat4*& a01, const vfloat4*& a10, const vfloat4*& a11,
    float& wx, float& wy)
{
    const int pxy = cell % 49;
    const int bn  = cell / 49;
    const int py  = pxy / 7;
    const int px  = pxy % 7;
    const int b   = bn / NN;

    const vfloat4 bx = *(const vfloat4*)(boxes + (size_t)bn * 4);
    const float y1 = bx.x, x1 = bx.y, y2 = bx.z, x2 = bx.w;
    const float h = y2 - y1, w = x2 - x1;

    // roi_level = clip(round(log2(sqrt(max(h*w,1e-12)) / (224/1024))), 2, 5); rintf = half-to-even.
    const float roi = log2f(sqrtf(fmaxf(h * w, 1e-12f)) * (1024.0f / 224.0f));
    int lvl = (int)rintf(roi);
    lvl = min(5, max(2, lvl));

    const float* feat;
    int H;
    switch (lvl) {
        case 2:  feat = p2; H = 256; break;
        case 3:  feat = p3; H = 128; break;
        case 4:  feat = p4; H = 64;  break;
        default: feat = p5; H = 32;  break;
    }
    const int W = H;

    const float ys = (y1 + h * ((float)py * (1.0f / 6.0f))) * (float)(H - 1);
    const float xs = (x1 + w * ((float)px * (1.0f / 6.0f))) * (float)(W - 1);
    const float y0f = floorf(ys), x0f = floorf(xs);
    wy = ys - y0f;
    wx = xs - x0f;
    const int y0 = min(H - 1, max(0, (int)y0f));
    const int yb = min(H - 1, max(0, (int)y0f + 1));
    const int x0 = min(W - 1, max(0, (int)x0f));
    const int xb = min(W - 1, max(0, (int)x0f + 1));

    const size_t base = (size_t)b * H * W * NC;
    a00 = (const vfloat4*)(feat + base + ((size_t)y0 * W + x0) * NC);
    a01 = (const vfloat4*)(feat + base + ((size_t)y0 * W + xb) * NC);
    a10 = (const vfloat4*)(feat + base + ((size_t)yb * W + x0) * NC);
    a11 = (const vfloat4*)(feat + base + ((size_t)yb * W + xb) * NC);
}

__device__ __forceinline__ vfloat4 bilerp4(vfloat4 v00, vfloat4 v01, vfloat4 v10, vfloat4 v11,
                                           float wx, float wy)
{
    vfloat4 top = v00 + wx * (v01 - v00);
    vfloat4 bot = v10 + wx * (v11 - v10);
    return top + wy * (bot - top);
}

__global__ __launch_bounds__(256) void roi_align_kernel(
    const float* __restrict__ boxes,
    const float* __restrict__ p2,
    const float* __restrict__ p3,
    const float* __restrict__ p4,
    const float* __restrict__ p5,
    float* __restrict__ out)
{
    const int lane = threadIdx.x & 63;
    const int wave = threadIdx.x >> 6;

    const int c0 = (blockIdx.x * 4 + wave) * 2;   // NCELLS divisible by 8, grid exact
    const int c1 = c0 + 1;

    const vfloat4 *a00, *a01, *a10, *a11;
    const vfloat4 *b00, *b01, *b10, *b11;
    float wx0, wy0, wx1, wy1;

    cell_setup(c0, boxes, p2, p3, p4, p5, a00, a01, a10, a11, wx0, wy0);
    cell_setup(c1, boxes, p2, p3, p4, p5, b00, b01, b10, b11, wx1, wy1);

    // Issue all 8 corner loads before any use -> 8 outstanding vmem per wave.
    const vfloat4 va00 = a00[lane];
    const vfloat4 va01 = a01[lane];
    const vfloat4 va10 = a10[lane];
    const vfloat4 va11 = a11[lane];
    const vfloat4 vb00 = b00[lane];
    const vfloat4 vb01 = b01[lane];
    const vfloat4 vb10 = b10[lane];
    const vfloat4 vb11 = b11[lane];

    const vfloat4 r0 = bilerp4(va00, va01, va10, va11, wx0, wy0);
    const vfloat4 r1 = bilerp4(vb00, vb01, vb10, vb11, wx1, wy1);

    // Non-temporal: keep the 100 MB output stream out of L2 so feature lines stay resident.
    vfloat4* o0 = (vfloat4*)(out + (size_t)c0 * NC) + lane;
    vfloat4* o1 = (vfloat4*)(out + (size_t)c1 * NC) + lane;
    __builtin_nontemporal_store(r0, o0);
    __builtin_nontemporal_store(r1, o1);
}

extern "C" void kernel_launch(void* const* d_in, const int* in_sizes, int n_in,
                              void* d_out, int out_size, void* d_ws, size_t ws_size,
                              hipStream_t stream) {
    const float* boxes = (const float*)d_in[0];
    const float* p2    = (const float*)d_in[1];
    const float* p3    = (const float*)d_in[2];
    const float* p4    = (const float*)d_in[3];
    const float* p5    = (const float*)d_in[4];
    float* out = (float*)d_out;

    const int n_blocks = NCELLS / CELLS_PER_BLOCK;  // 12250
    roi_align_kernel<<<n_blocks, 256, 0, stream>>>(boxes, p2, p3, p4, p5, out);
}